// Round 5
// baseline (1603.958 us; speedup 1.0000x reference)
//
#include <hip/hip_runtime.h>
#include <hip/hip_bf16.h>

#define NN 512
#define SSAMP 64
#define NSTEP 400
#define CW 8          // compute waves per seq block
#define SEQBLK 64     // seq grid

typedef __attribute__((ext_vector_type(4))) float f32x4;
typedef __attribute__((ext_vector_type(8))) short s16x8;

// ---------- helpers ----------
__device__ __forceinline__ float wsum(float v){
  v += __shfl_xor(v, 32, 64);
  v += __shfl_xor(v, 16, 64);
  v += __shfl_xor(v,  8, 64);
  v += __shfl_xor(v,  4, 64);
  v += __shfl_xor(v,  2, 64);
  v += __shfl_xor(v,  1, 64);
  return v;
}
__device__ __forceinline__ float tanh_pos(float u){ // u >= 0
  float e = __expf(2.0f*u);
  return 1.0f - 2.0f/(e+1.0f);
}
__device__ __forceinline__ float tanh_gen(float u){
  float a = fabsf(u);
  float e = __expf(2.0f*a);
  float t = 1.0f - 2.0f/(e+1.0f);
  return copysignf(t, u);
}
__device__ __forceinline__ float h_tf(float a, float b, float d, float z){
  float x = fmaf(a, z, -b);
  float num = 1e-5f + fabsf(x);
  float den = 1e-5f*d + fabsf(1.0f - __expf(-d*x));
  return num/den;
}

// ---------- phase 1: w = 0.5*(exp(gc)*sc + (exp(gc)*sc)^T), normsq ----------
__global__ __launch_bounds__(256) void prep_w_kernel(
    const float* __restrict__ sc, const float* __restrict__ gc,
    float* __restrict__ w, float* __restrict__ normsq){
  int idx = blockIdx.x*256 + threadIdx.x;
  int i = idx >> 9, j = idx & 511;
  float a = __expf(gc[idx])*sc[idx];
  float b = __expf(gc[j*NN+i])*sc[j*NN+i];
  float wij = 0.5f*(a + b);
  w[idx] = wij;
  float p = wsum(wij*wij);
  if ((threadIdx.x & 63) == 0) atomicAdd(normsq, p);
}

// ---------- phase 1b: lap = (w - diag(rowsum(w))) / norm ----------
__global__ __launch_bounds__(64) void prep_lap_kernel(
    const float* __restrict__ w, const float* __restrict__ normsq,
    float* __restrict__ lap){
  int i = blockIdx.x;
  int l = threadIdx.x; // 0..63
  float vals[8]; float s = 0.f;
  #pragma unroll
  for (int j=0;j<8;j++){ vals[j] = w[i*NN + j*64 + l]; s += vals[j]; }
  float rs = wsum(s);
  float rn = 1.0f/sqrtf(normsq[0]);
  #pragma unroll
  for (int j=0;j<8;j++){
    int col = j*64 + l;
    float x = vals[j] - (col==i ? rs : 0.0f);
    lap[i*NN+col] = x*rn;
  }
}

// ---------- phase 1c: lap f32 -> bf16 ----------
__global__ __launch_bounds__(256) void lap_bf_kernel(
    const float* __restrict__ lap, __hip_bfloat16* __restrict__ lb){
  int i = blockIdx.x*256 + threadIdx.x;
  lb[i] = __float2bfloat16(lap[i]);
}

// ---------- phase 2a: transpose e0: [t][n][s] f32 -> [t][s][n] bf16 ----------
__global__ __launch_bounds__(256) void e0t_kernel(
    const float* __restrict__ nE0, __hip_bfloat16* __restrict__ th){
  __shared__ float tile[64][65];
  int t = blockIdx.y, c = blockIdx.x;              // c: node chunk (8 x 64)
  const float* src = nE0 + ((size_t)t*NN + c*64)*SSAMP;
  int tid = threadIdx.x;
  int r0 = tid>>2, c4 = (tid&3)*16;
  #pragma unroll
  for (int i=0;i<4;i++){
    float4 v = *(const float4*)(src + r0*64 + c4 + i*4);
    tile[r0][c4+i*4+0]=v.x; tile[r0][c4+i*4+1]=v.y;
    tile[r0][c4+i*4+2]=v.z; tile[r0][c4+i*4+3]=v.w;
  }
  __syncthreads();
  int s = tid>>2, nseg = (tid&3)*16;
  __hip_bfloat16 hs[16];
  #pragma unroll
  for (int i=0;i<16;i++) hs[i] = __float2bfloat16(tile[nseg+i][s]);
  size_t doff = ((size_t)t*64 + s)*NN + c*64 + nseg;
  *(uint4*)(th + doff)     = *(uint4*)&hs[0];
  *(uint4*)(th + doff + 8) = *(uint4*)&hs[8];
}

// ---------- phase 2b: L0[t][n][s] = lap @ e0[t] via bf16 MFMA ----------
// C^T orientation: D(MxN) = A(e0T, 64 x 512) * B(lap, 512 x 512); lap rows are
// K-contiguous (natural row-major, n=row). D: col(n)=lane&15, row(s)=(lane>>4)*4+reg.
__global__ __launch_bounds__(256) void mfma_gemm_kernel(
    const __hip_bfloat16* __restrict__ A, const __hip_bfloat16* __restrict__ B,
    __hip_bfloat16* __restrict__ L0){
  int t = blockIdx.y;
  int nb = blockIdx.x;                       // 0..3, 128 cols each
  int w  = threadIdx.x>>6, l = threadIdx.x&63;
  int lr = l&15, lg = l>>4;
  f32x4 acc[4][2] = {};
  const short* ap = (const short*)A + ((size_t)t*64 + lr)*NN + lg*8;
  int col0 = nb*128 + w*32 + lr;
  const short* bp = (const short*)B + (size_t)col0*NN + lg*8;
  for (int k0=0; k0<NN; k0+=32){
    s16x8 a[4], b[2];
    #pragma unroll
    for (int mt=0;mt<4;mt++) a[mt] = *(const s16x8*)(ap + mt*16*NN + k0);
    #pragma unroll
    for (int nt=0;nt<2;nt++) b[nt] = *(const s16x8*)(bp + nt*16*NN + k0);
    #pragma unroll
    for (int mt=0;mt<4;mt++)
      #pragma unroll
      for (int nt=0;nt<2;nt++)
        acc[mt][nt] = __builtin_amdgcn_mfma_f32_16x16x32_bf16(a[mt], b[nt], acc[mt][nt],0,0,0);
  }
  #pragma unroll
  for (int mt=0;mt<4;mt++)
    #pragma unroll
    for (int nt=0;nt<2;nt++){
      int n = col0 + nt*16;                  // includes lr
      int s = mt*16 + lg*4;
      ushort4 h;
      h.x = __hip_bfloat16_raw(__float2bfloat16(acc[mt][nt].x)).x;
      h.y = __hip_bfloat16_raw(__float2bfloat16(acc[mt][nt].y)).x;
      h.z = __hip_bfloat16_raw(__float2bfloat16(acc[mt][nt].z)).x;
      h.w = __hip_bfloat16_raw(__float2bfloat16(acc[mt][nt].w)).x;
      *(ushort4*)((unsigned short*)L0 + ((size_t)t*NN + n)*SSAMP + s) = h;
    }
}

// ---------- phase 3: sequential 400-step dynamics ----------
// 64 blocks x 576 threads: waves 0..7 compute (1 node each), wave 8 = comm.
// Comm wave is the only global poller (64 device-wide); it LDS-broadcasts the
// 512 Em values + release-flag. Exchange: (tag32<<32 | f32) u64 agent atomics,
// double-buffered by step parity. Tag+value share one word -> no fences.
__global__ __launch_bounds__(576) void seq_kernel(
    const float* __restrict__ external, const float* __restrict__ hx,
    const float* __restrict__ lap, const __hip_bfloat16* __restrict__ L0,
    const float* __restrict__ nE0, const float* __restrict__ nI0,
    const float* __restrict__ nE,  const float* __restrict__ nI,
    const float* __restrict__ nB,
    const float* __restrict__ gp,   const float* __restrict__ gEEp,
    const float* __restrict__ gIEp, const float* __restrict__ gEIp,
    const float* __restrict__ stdinp, const float* __restrict__ stdoutp,
    unsigned long long* __restrict__ xbuf,  // 2*512 packed words
    float* __restrict__ out)
{
  __shared__ float hxs[2][NN];
  __shared__ int flag;
  const int tid  = threadIdx.x;
  const int wv   = tid >> 6, lane = tid & 63;
  if (tid == 0) flag = 0;

  if (wv == CW){
    // ---------------- communicator wave ----------------
    __syncthreads();   // flag init visible
    #pragma unroll 1
    for (int t=0; t<NSTEP; ++t){
      const unsigned want = (unsigned)(t+1);
      unsigned long long* bc = xbuf + (size_t)(t&1)*NN;
      unsigned long long u[8];
      for(;;){
        #pragma unroll
        for (int j=0;j<8;j++)
          u[j] = __hip_atomic_load(&bc[j*64+lane], __ATOMIC_RELAXED, __HIP_MEMORY_SCOPE_AGENT);
        int ok = 1;
        #pragma unroll
        for (int j=0;j<8;j++) ok &= (int)((unsigned)(u[j]>>32) == want);
        if (__all(ok)) break;
        __builtin_amdgcn_s_sleep(1);
      }
      #pragma unroll
      for (int j=0;j<8;j++)
        hxs[t&1][j*64+lane] = __uint_as_float((unsigned)u[j]);
      if (lane==0)
        __hip_atomic_store(&flag, t+1, __ATOMIC_RELEASE, __HIP_MEMORY_SCOPE_WORKGROUP);
    }
    return;
  }

  // ---------------- compute waves ----------------
  const int n = blockIdx.x*CW + wv;

  const float g    = gp[0];
  const float gEE  = 0.001f + fmaxf(gEEp[0], 0.f);
  const float gIE  = 0.001f + fmaxf(gIEp[0], 0.f);
  const float gEI  = 0.001f + fmaxf(gEIp[0], 0.f);
  const float sdin = 0.02f  + fmaxf(stdinp[0], 0.f);
  const float sdout=          fmaxf(stdoutp[0], 0.f);
  const float sqin = 0.22360679774997896f * sdin;

  float hxE = hx[n*6+0], hxI = hx[n*6+1];
  float xs  = hx[n*6+2], fs  = hx[n*6+3], vs = hx[n*6+4], qs = hx[n*6+5];

  float lr[8];
  #pragma unroll
  for (int j=0;j<8;j++) lr[j] = lap[(size_t)n*NN + j*64 + lane];

  // publish version 0 (tag=1) into bank 0
  if (lane==0)
    __hip_atomic_store(&xbuf[n], (1ULL<<32) | (unsigned long long)__float_as_uint(hxE),
                       __ATOMIC_RELAXED, __HIP_MEMORY_SCOPE_AGENT);

  const size_t nsbase = (size_t)n*SSAMP + lane;
  float c_e0 = nE0[nsbase];
  float c_i0 = nI0[nsbase];
  float c_eE = nE [nsbase];
  float c_eI = nI [nsbase];
  float c_L0 = __bfloat162float(L0[nsbase]);
  float c_ex = external[n*400 + 0];

  __syncthreads();   // flag init visible

  #pragma unroll 1
  for (int t=0; t<NSTEP; ++t){
    // prefetch next step's per-thread data (1-step distance)
    int tn = (t+1 < NSTEP) ? t+1 : t;
    size_t offn = (size_t)tn*NN*SSAMP + nsbase;
    float p_e0 = nE0[offn], p_i0 = nI0[offn], p_eE = nE[offn], p_eI = nI[offn];
    float p_L0 = __bfloat162float(L0[offn]);
    float p_ex = external[n*400 + (tn%20)*20 + (tn/20)];

    // ---- exchange-independent work ----
    float E = fmaf(0.02f , c_e0, hxE);
    float I = fmaf(0.001f, c_i0, hxI);
    float II = tanh_pos(fmaxf(fmaf(gEI, E, 0.224f) - I, 0.f));
    float rI = h_tf(615.0f, 177.0f, 0.087f, II);
    float In = I + 0.05f*fmaf(-100.0f, I, rI) + sqin*c_eI;
    float Ip = tanh_pos(fmaxf(In, 0.f));
    float Im = fmaxf(wsum(Ip)*0.015625f, 1e-5f);
    float IEpre = 0.32f + 0.02f*c_ex + gEE*E + g*0.02f*c_L0 - gIE*I;

    // ---- wait for comm wave's broadcast of version t ----
    while (__hip_atomic_load(&flag, __ATOMIC_ACQUIRE, __HIP_MEMORY_SCOPE_WORKGROUP) < t+1){}

    // ---- matvec from LDS broadcast ----
    float mv = 0.f;
    #pragma unroll
    for (int j=0;j<8;j++) mv = fmaf(lr[j], hxs[t&1][j*64+lane], mv);
    float lapHx = wsum(mv);

    float IE = tanh_pos(fmaxf(fmaf(g, lapHx, IEpre), 0.f));
    float rE = h_tf(310.0f, 125.0f, 0.16f, IE);
    float En = E + 0.05f*fmaf(0.641f*(1.0f-E), rE, -10.0f*E) + sqin*c_eE;
    float Ep = tanh_pos(fmaxf(En, 0.f));
    float Em = fmaxf(wsum(Ep)*0.015625f, 1e-5f);

    // ---- publish version t+1 ASAP ----
    if (lane==0)
      __hip_atomic_store(&xbuf[(size_t)((t+1)&1)*NN + n],
                         ((unsigned long long)(t+2)<<32) | (unsigned long long)__float_as_uint(Em),
                         __ATOMIC_RELAXED, __HIP_MEMORY_SCOPE_AGENT);

    // ---- hemodynamics (off critical path) ----
    float va = __expf(3.125f*__logf(vs));
    float xn = xs + 0.05f*(Em - xs*1.5384615384615385f - (fs-1.0f)*2.4390243902439024f);
    float fn = fs + 0.05f*xs;
    float vn = vs + 0.05f*(fs - va)*1.0204081632653061f;
    float qn = qs + 0.05f*( fs*(1.0f - __expf(-0.41551544396166582f/fs))*2.9411764705882355f
                            - qs*va/vs )*1.0204081632653061f;
    xs = tanh_gen(xn);
    fs = 1.0f + tanh_gen(fn - 1.0f);
    vs = 1.0f + tanh_gen(vn - 1.0f);
    qs = 1.0f + tanh_gen(qn - 1.0f);
    hxE = Em; hxI = Im;

    if (((t+1) % 20) == 0 && lane==0){
      int tr = t/20;
      float eb = nB[tr*NN + n];
      float bold = sdout*eb + 5.882352941176471f*( 2.38f*(1.0f-qs)
                   + 2.0f*(1.0f - qs/vs) + 0.48f*(1.0f-vs) );
      out[n*20 + tr] = bold;
    }

    c_e0=p_e0; c_i0=p_i0; c_eE=p_eE; c_eI=p_eI; c_L0=p_L0; c_ex=p_ex;
  }
}

// ---------- host ----------
extern "C" void kernel_launch(void* const* d_in, const int* in_sizes, int n_in,
                              void* d_out, int out_size, void* d_ws, size_t ws_size,
                              hipStream_t stream) {
  (void)in_sizes; (void)n_in; (void)out_size; (void)ws_size;
  const float* external = (const float*)d_in[0];
  const float* hx   = (const float*)d_in[1];
  const float* sc   = (const float*)d_in[3];
  const float* gc   = (const float*)d_in[4];
  const float* gp   = (const float*)d_in[5];
  const float* gEE  = (const float*)d_in[6];
  const float* gIE  = (const float*)d_in[7];
  const float* gEI  = (const float*)d_in[8];
  const float* stdi = (const float*)d_in[9];
  const float* stdo = (const float*)d_in[10];
  const float* nE0  = (const float*)d_in[11];
  const float* nI0  = (const float*)d_in[12];
  const float* nE   = (const float*)d_in[13];
  const float* nI   = (const float*)d_in[14];
  const float* nB   = (const float*)d_in[15];
  float* out = (float*)d_out;

  // layout (51.5 MiB): [16K ctrl][1M lap f32][0.5M lap bf16][25M th][25M L0]
  // w (1 MiB, prep-only) is overlaid on th.
  char* ws = (char*)d_ws;
  const size_t MB = 1048576;
  float*    normsq = (float*)ws;                               // 4 B
  unsigned long long* xbuf = (unsigned long long*)(ws + 256);  // 8 KB
  float* lap            = (float*)(ws + 16384);                // 1 MiB
  __hip_bfloat16* lapbf = (__hip_bfloat16*)(ws + 16384 + 1*MB);// 512 KiB
  char* thp             = ws + 16384 + 1*MB + 512*1024;        // 25 MiB
  float* w              = (float*)thp;                         // overlay (prep only)
  __hip_bfloat16* th    = (__hip_bfloat16*)thp;
  __hip_bfloat16* L0    = (__hip_bfloat16*)(thp + (size_t)NSTEP*64*NN*2);

  hipMemsetAsync(ws, 0, 16384, stream);
  prep_w_kernel  <<<1024, 256, 0, stream>>>(sc, gc, w, normsq);
  prep_lap_kernel<<< 512,  64, 0, stream>>>(w, normsq, lap);
  lap_bf_kernel  <<<1024, 256, 0, stream>>>(lap, lapbf);
  e0t_kernel     <<<dim3(8, NSTEP), 256, 0, stream>>>(nE0, th);
  mfma_gemm_kernel<<<dim3(4, NSTEP), 256, 0, stream>>>(th, lapbf, L0);
  seq_kernel<<<SEQBLK, 576, 0, stream>>>(external, hx, lap, L0,
      nE0, nI0, nE, nI, nB, gp, gEE, gIE, gEI, stdi, stdo, xbuf, out);
}